// Round 5
// baseline (237.294 us; speedup 1.0000x reference)
//
#include <hip/hip_runtime.h>

// Blocks SNN forward: T=1024, TB=8, B=32, N=1024.
// Producer/consumer wave pair per 64 chains (R11 structure), coarsened to
// G=4 blocks per barrier iteration.
//
// R12 rationale: R7 (reg prefetch), R9 (compiler waits), R11 (producer/
// consumer) all converged on ~84us = ~1575cy/block despite completely
// different memory schedules -> the floor is NOT memory latency; it is the
// per-block sync quantum: per 8-timestep block every version paid
// lgkm-in (~120cy) + math (~280cy) + lgkm-out (~120cy) + barrier +
// producer-side latencies, all serialized by a block-granular barrier.
// 128 lockstep round-trips x ~1500cy = 84us. Coarsening to G=4 blocks per
// barrier (32 iterations) amortizes every fixed latency 4x while keeping
// the proven math (absmax 0.0 since R8) and DMA layout verbatim.
//
// Protocol (RING=16 input tiles = 4 groups of 4; sbuf ping-pong of 4):
//   iter j (between barrier j-1 and barrier j), j = 0..31:
//     consumer: ds_read group (j&3) tiles; compute blocks 4j..4j+3
//               (chained carry); stage spikes into sbuf[j&1][0..3];
//               lgkmcnt(0); s_barrier.
//     producer: drain sbuf[(j-1)&1] -> 8 stores (blocks 4(j-1)..4j-1);
//               DMA group ((j+2)&3) tiles (8 ops, blocks 4(j+2)..4j+11);
//               s_waitcnt vmcnt(W_j); s_barrier.
//   vmcnt bookkeeping (in-order counter, 8 stores + 8 DMAs per steady
//   iter): target = group (j+1) DMAs, issued at iter j-1:
//     prologue: issue groups 0,1 (16 ops), wait vmcnt(8)  [group 0 done]
//     j=0:  no drain, DMA group 2, W=8   [group 1 done]
//     j=1..29: steady, W=16              [group j+1 done]
//     j=30: drain only, W=8              [group 31's tiles done]
//     j=31: drain only, no wait; post-loop drains iter-31 spikes.
//   Slot reuse race-free: group (j+2)&3 written at iter j was last read
//   at iter j-2, finished before barrier j-2. sbuf halves alternate.
// Raw s_barrier + counted vmcnt (never __syncthreads: would drain the
// producer pipeline). asm "" memory clobbers fence IR code motion around
// barriers.

constexpr int T_LEN = 1024;
constexpr int TB    = 8;
constexpr int NBLK  = T_LEN / TB;   // 128
constexpr int BATCH = 32;
constexpr int NOUT  = 1024;
constexpr int BN    = BATCH * NOUT; // 32768 chains
constexpr int G     = 4;            // blocks per barrier iteration
constexpr int NITER = NBLK / G;     // 32
constexpr int RING  = 16;           // input tile ring (4 groups of G)

typedef float f4 __attribute__((ext_vector_type(4)));

__device__ __forceinline__ void dma16(const float* g, float* l) {
    __builtin_amdgcn_global_load_lds(
        (const __attribute__((address_space(1))) void*)g,
        (__attribute__((address_space(3))) void*)l, 16, 0, 0);
}

__global__ __launch_bounds__(128, 1)
void snn_blocks_kernel(const float* __restrict__ x,
                       const float* __restrict__ beta_raw,
                       const float* __restrict__ p_raw,
                       const float* __restrict__ b_raw,
                       float* __restrict__ out)
{
    __shared__ float inbuf[RING][TB * 64];   // 32KB DMA-written input ring
    __shared__ float sbuf[2][G][TB * 64];    // 16KB ping-pong spike staging

    const int tid  = threadIdx.x;
    const int lane = tid & 63;
    const int wid  = tid >> 6;              // 0 = consumer, 1 = producer
    const int wg0  = blockIdx.x * 64;       // flat chain offset of this WG

    if (wid == 1) {
        // ================= PRODUCER WAVE (all vmem) =================
        // lane p covers row (p>>4), cols (p&15)*4..+3 == DMA HW layout:
        // lane p writes LDS bytes [16p,16p+16) of each tile.
        const int rowoff = lane >> 4;
        const int coloff = wg0 + (lane & 15) * 4;
        const float* xbase = x   + (ptrdiff_t)rowoff * BN + coloff;
        float*       obase = out + (ptrdiff_t)rowoff * BN + coloff;

        auto dmaGroup = [&](int j2) {        // DMA the G tiles of iter j2
#pragma unroll
            for (int i = 0; i < G; ++i) {
                const int b = j2 * G + i;
                const float* g = xbase + (ptrdiff_t)(b * TB) * BN;
                float* l = &inbuf[b & (RING - 1)][0];
                dma16(g,          l);
                dma16(g + 4 * BN, l + 256);
            }
        };
        auto drainIter = [&](int j) {        // store spikes staged at iter j
#pragma unroll
            for (int i = 0; i < G; ++i) {
                const float* sf = &sbuf[j & 1][i][0];
                f4 s0 = *(const f4*)(sf + lane * 4);
                f4 s1 = *(const f4*)(sf + 256 + lane * 4);
                const int b = j * G + i;
                *(f4*)(obase + (ptrdiff_t)(b * TB) * BN)     = s0;
                *(f4*)(obase + (ptrdiff_t)(b * TB + 4) * BN) = s1;
            }
        };

        // prologue: groups 0 and 1 (blocks 0..7)
        dmaGroup(0);
        dmaGroup(1);
        asm volatile("s_waitcnt vmcnt(8)" ::: "memory");   // group 0 done
        __builtin_amdgcn_s_barrier();
        asm volatile("" ::: "memory");

        // j = 0: no drain yet
        dmaGroup(2);
        asm volatile("s_waitcnt vmcnt(8)" ::: "memory");   // group 1 done
        __builtin_amdgcn_s_barrier();
        asm volatile("" ::: "memory");

        // j = 1..29: steady state
#pragma unroll 1
        for (int j = 1; j <= 29; ++j) {
            drainIter(j - 1);
            dmaGroup(j + 2);
            asm volatile("s_waitcnt vmcnt(16)" ::: "memory"); // group j+1
            __builtin_amdgcn_s_barrier();
            asm volatile("" ::: "memory");
        }

        // j = 30: ring drained past block 127
        drainIter(29);
        asm volatile("s_waitcnt vmcnt(8)" ::: "memory");   // group 31 done
        __builtin_amdgcn_s_barrier();
        asm volatile("" ::: "memory");

        // j = 31
        drainIter(30);
        __builtin_amdgcn_s_barrier();
        asm volatile("" ::: "memory");

        // post-loop: spikes of iter 31 (blocks 124..127), visible via
        // consumer's lgkmcnt(0) before the final barrier.
        drainIter(31);
    } else {
        // ================= CONSUMER WAVE (zero vmem) =================
        const int gid = wg0 + lane;         // = b*NOUT + n
        const int n   = gid & (NOUT - 1);

        // clamped properties (f64)
        double beta = (double)beta_raw[n];
        beta = beta < 0.001 ? 0.001 : (beta > 0.999 ? 0.999 : beta);
        double p = fabs((double)p_raw[n]);
        p = p > 0.999 ? 0.999 : p;
        double bb = fabs((double)b_raw[n]);
        bb = bb < 0.001 ? 0.001 : (bb > 1.0 ? 1.0 : bb);
        const double inv_p = 1.0 / p;

        double ppow[9];
        ppow[0] = 1.0;
#pragma unroll
        for (int i = 1; i <= 8; ++i) ppow[i] = ppow[i - 1] * p;
        double bbp[8];
#pragma unroll
        for (int t = 0; t < 8; ++t) bbp[t] = bb * ppow[t + 1];
        const double pp2 = ppow[2], pp4 = ppow[4], pp8 = ppow[8];

        double m = 0.0, a = 0.0;
        int maskf = 0, firstp = 0;

        __builtin_amdgcn_s_barrier();       // matches producer prologue
        asm volatile("" ::: "memory");

#pragma unroll 1
        for (int j = 0; j < NITER; ++j) {
            const int g0 = (j & 3) * G;     // base tile slot of this group

#pragma unroll
            for (int i = 0; i < G; ++i) {
                float cur[8];
#pragma unroll
                for (int t = 0; t < 8; ++t)
                    cur[t] = inbuf[g0 + i][t * 64 + lane];

                // ---- header: adaptation update from prev-block stats ----
                double pf1 = p;                        // -> p^(firstp+1)
                pf1 *= (firstp & 1) ? p   : 1.0;
                pf1 *= (firstp & 2) ? pp2 : 1.0;
                pf1 *= (firstp & 4) ? pp4 : 1.0;
                const int dsteps = firstp ^ 7;         // 7 - firstp
                double pd = (dsteps & 1) ? p : 1.0;
                pd *= (dsteps & 2) ? pp2 : 1.0;
                pd *= (dsteps & 4) ? pp4 : 1.0;
                const double new_a = (a * pf1 + inv_p) * pd;
                double vinit;
                if (maskf) { a = new_a;   vinit = 0.0; }  // v_init = 0
                else       { a = pp8 * a; vinit = m;   }  // keep int_mem

                // refractory mask: prev z[t]==0 <=> t < firstp (if maskf)
                const int zmask = maskf ? ((1 << firstp) - 1) : 0;

                int fbits = 0;
                double mm = vinit;
#pragma unroll
                for (int t = 0; t < 8; ++t) {
                    const float xf = ((zmask >> t) & 1) ? 0.0f : cur[t];
                    mm = beta * mm + (double)xf;          // causal decay sum
                    const double vth = 1.0 + bbp[t] * a;  // 1+bb*p^(t+1)*a
                    fbits |= (mm - vth > 0.0) ? (1 << t) : 0; // heaviside
                }
                m = mm;
                maskf  = (fbits != 0);
                firstp = fbits ? __builtin_ctz(fbits) : 0;

                // stage spikes (one-hot at firstp) for producer drain
#pragma unroll
                for (int t = 0; t < 8; ++t)
                    sbuf[j & 1][i][t * 64 + lane] =
                        (maskf && t == firstp) ? 1.0f : 0.0f;
            }

            asm volatile("s_waitcnt lgkmcnt(0)" ::: "memory");
            __builtin_amdgcn_s_barrier();
            asm volatile("" ::: "memory");
        }
    }
}

extern "C" void kernel_launch(void* const* d_in, const int* in_sizes, int n_in,
                              void* d_out, int out_size, void* d_ws, size_t ws_size,
                              hipStream_t stream) {
    const float* x        = (const float*)d_in[0];
    const float* beta_raw = (const float*)d_in[1];
    const float* p_raw    = (const float*)d_in[2];
    const float* b_raw    = (const float*)d_in[3];
    float* out            = (float*)d_out;

    dim3 grid(BN / 64);   // 512 WGs x (1 consumer + 1 producer) wave
    dim3 block(128);
    snn_blocks_kernel<<<grid, block, 0, stream>>>(x, beta_raw, p_raw, b_raw, out);
}